// Round 5
// baseline (332.977 us; speedup 1.0000x reference)
//
#include <hip/hip_runtime.h>

// Problem constants (fixed by the reference)
#define Bn 8
#define Nn 50000
#define En 800000
#define Dd 64
#define CAP 64  // bucket capacity per node; P(in-degree >= 64) ~ 1e-18 (Binomial(800k,1/50k))

typedef __attribute__((ext_vector_type(8))) unsigned short ushort8;
typedef __attribute__((ext_vector_type(8))) __bf16 bf16x8;
typedef __attribute__((ext_vector_type(4))) float floatx4;
typedef __attribute__((ext_vector_type(2))) int intx2;

__device__ __forceinline__ unsigned short f2bf(float f) {
  unsigned int u = __builtin_bit_cast(unsigned int, f);
  u = (u + 0x7FFFu + ((u >> 16) & 1u)) >> 16;  // RNE
  return (unsigned short)u;
}

// XOR-swizzled byte offset into a [128-row][256B] LDS tile.
__device__ __forceinline__ int swz(int row, int byte_in_row) {
  return (row * 256 + byte_in_row) ^ ((row & 7) << 4);
}

// ---- 1. fused: x (f32) -> xb_t (bf16, TRANSPOSED [node][batch][dim]) +
//      edge bucket build + W/bias prep ----
// xb_t[n][b][d]: one node = 1KB contiguous covering all 8 batches -> k_main
// gathers each edge ONCE for all batches (was 8x). x/ei dead after this
// kernel -> nt loads; bucket scatter nt store (no write-allocate RMW fetch).
__global__ __launch_bounds__(256) void k_fconv(const float* __restrict__ x,
                                               unsigned short* __restrict__ xb,
                                               const int* __restrict__ ei,
                                               int* __restrict__ deg,
                                               unsigned short* __restrict__ bucket,
                                               const float* __restrict__ Ws,
                                               const float* __restrict__ Wn,
                                               const float* __restrict__ bs,
                                               const float* __restrict__ bn,
                                               unsigned short* __restrict__ Wb,
                                               float* __restrict__ bb) {
  const size_t gid = (size_t)blockIdx.x * 256 + threadIdx.x;
  const size_t i = gid * 8;  // grid sized exactly: 3.2M threads x 8 f32
  const floatx4 v0 = __builtin_nontemporal_load((const floatx4*)(x + i));
  const floatx4 v1 = __builtin_nontemporal_load((const floatx4*)(x + i + 4));
  ushort8 o;
  o[0] = f2bf(v0.x); o[1] = f2bf(v0.y); o[2] = f2bf(v0.z); o[3] = f2bf(v0.w);
  o[4] = f2bf(v1.x); o[5] = f2bf(v1.y); o[6] = f2bf(v1.z); o[7] = f2bf(v1.w);
  // x is [b][n][d]; i = ((b*Nn)+n)*64 + d, d multiple of 8
  const unsigned int b = (unsigned int)(i / (Nn * (size_t)Dd));
  const unsigned int r = (unsigned int)(i - (size_t)b * (Nn * Dd));
  const unsigned int n = r >> 6, d = r & 63;
  // transposed store: 8 lanes of a node -> one 128B line at n*1KB + b*128B
  *(ushort8*)(xb + (size_t)n * 512 + b * 64 + d) = o;
  if ((gid & 3) == 0) {  // gid>>2 covers exactly [0, En): 16 edges per wave
    const size_t e = gid >> 2;
    const intx2 ep = __builtin_nontemporal_load((const intx2*)(ei + 2 * e));  // [src,dst]
    const int p = atomicAdd(&deg[ep.y], 1);
    if (p < CAP)
      __builtin_nontemporal_store((unsigned short)ep.x, &bucket[((size_t)ep.y << 6) + p]);
  }
  if (gid < 1024) {
    // Wb fragment f = t*4+k, lane ln: 8 bf16 = W?[o=t*16+col][kd=k*32+quad*8 ..+8]
    const int f = (int)gid >> 6, ln = (int)gid & 63;
    const int t = f >> 2, k = f & 3;
    const int col = ln & 15, quad = ln >> 4;
    const int orow = t * 16 + col;
    const int kd = k * 32 + quad * 8;  // multiple of 8; never straddles 64
    const float* wsrc = (kd < 64) ? (Ws + orow * 64 + kd) : (Wn + orow * 64 + (kd - 64));
    ushort8 u;
    #pragma unroll
    for (int j = 0; j < 8; ++j) u[j] = f2bf(wsrc[j]);
    *(ushort8*)(Wb + gid * 8) = u;
  }
  if (gid < 64) bb[gid] = bs[gid] + bn[gid];
}

// ---- 2. fused: bucket-pull aggregate (ALL 8 batches per edge) + MFMA ----
// Block = 16 nodes x 8 batches (3125 blocks, 50000 exactly: no bounds checks).
// Wave handles 4 nodes sequentially: per edge, the 64 lanes load the src
// node's full 1KB (lane l: batch l>>3, dims (l&7)*8) -> one gather per edge
// total (was 8), loop bound wave-uniform (zero divergence padding).
// LDS A: 128 rows (node-major: row = nl*8 + batch) x 256B, swizzled, 32KB.
// Each wave writes/reads only rows 32w..32w+31 -> still barrier-free.
__global__ __launch_bounds__(256, 4) void k_main(
    const unsigned short* __restrict__ xb, const unsigned short* __restrict__ bucket,
    const int* __restrict__ deg, const unsigned short* __restrict__ Wb,
    const float* __restrict__ bb, float* __restrict__ out) {
  __shared__ __align__(16) unsigned short A[128 * 128];  // 32KB

  const int tid = threadIdx.x;
  const int lane = tid & 63;
  const int wave = __builtin_amdgcn_readfirstlane(tid >> 6);  // provably uniform ->
  const int node0 = blockIdx.x * 16;                          // scalar deg/bucket loads
  char* Ac = (char*)A;
  const int lofs = lane * 8;  // ushort offset into a node's 1KB row

  // ---- preload per node: self row + first index chunk + degree ----
  uint4 selfq[4], idx0[4];
  int cntq[4];
  #pragma unroll
  for (int q = 0; q < 4; ++q) {
    const int node = node0 + wave * 4 + q;
    cntq[q] = min(deg[node], CAP);
    selfq[q] = *(const uint4*)(xb + (size_t)node * 512 + lofs);
    idx0[q] = *(const uint4*)(bucket + ((size_t)node << 6));  // slots 0..7 (broadcast)
  }
  #pragma unroll
  for (int q = 0; q < 4; ++q) {  // self half of each row
    const int row = (wave * 4 + q) * 8 + (lane >> 3);
    *(uint4*)(Ac + swz(row, (lane & 7) * 16)) = selfq[q];
  }

  // ---- Phase A: per-node edge stream, 8 gathers in flight, idx prefetch ----
  for (int q = 0; q < 4; ++q) {
    const int node = node0 + wave * 4 + q;
    const int cnt = cntq[q];
    const unsigned short* bkt = bucket + ((size_t)node << 6);
    const int nch = (cnt + 7) >> 3;
    float acc[8] = {0.f, 0.f, 0.f, 0.f, 0.f, 0.f, 0.f, 0.f};
    uint4 e = idx0[q];
    for (int c = 0; c < nch; ++c) {
      uint4 ne = e;
      if (c + 1 < nch) ne = *(const uint4*)(bkt + (c + 1) * 8);  // prefetch
      const unsigned int ew[4] = {e.x, e.y, e.z, e.w};
      uint4 g[8];
      float m[8];
      #pragma unroll
      for (int t = 0; t < 8; ++t) {  // issue all 8 1KB-wave gathers first
        unsigned int s = (ew[t >> 1] >> ((t & 1) * 16)) & 0xFFFFu;
        const bool live = (c * 8 + t) < cnt;
        m[t] = live ? 1.0f : 0.0f;
        s = live ? s : (unsigned)(Nn - 1);  // pad -> hot row
        g[t] = *(const uint4*)(xb + (size_t)s * 512 + lofs);
      }
      #pragma unroll
      for (int t = 0; t < 8; ++t) {
        const unsigned int* w = (const unsigned int*)&g[t];
        #pragma unroll
        for (int j = 0; j < 4; ++j) {  // 2 bf16 per u32; masked fma accumulate
          acc[2 * j]     = fmaf(m[t], __builtin_bit_cast(float, w[j] << 16), acc[2 * j]);
          acc[2 * j + 1] = fmaf(m[t], __builtin_bit_cast(float, w[j] & 0xFFFF0000u), acc[2 * j + 1]);
        }
      }
      e = ne;
    }
    ushort8 av;
    #pragma unroll
    for (int j = 0; j < 8; ++j) av[j] = f2bf(acc[j]);
    const int row = (wave * 4 + q) * 8 + (lane >> 3);
    *(ushort8*)(Ac + swz(row, 128 + (lane & 7) * 16)) = av;  // agg half
  }
  // no __syncthreads(): wave consumes only the rows it wrote

  // ---- Phase B: 16x16x32 bf16 MFMA. Wave w: M-tiles m=2w,2w+1 (rows 32w..+31) ----
  const int col = lane & 15;
  const int quad = lane >> 4;
  #pragma unroll
  for (int mi = 0; mi < 2; ++mi) {
    const int mt = wave * 2 + mi;
    bf16x8 af[4];
    {
      const int row = mt * 16 + col;
      #pragma unroll
      for (int k = 0; k < 4; ++k)
        af[k] = __builtin_bit_cast(bf16x8, *(const ushort8*)(Ac + swz(row, k * 64 + quad * 16)));
    }
    #pragma unroll
    for (int t = 0; t < 4; ++t) {
      floatx4 acc = {0.f, 0.f, 0.f, 0.f};
      #pragma unroll
      for (int k = 0; k < 4; ++k) {
        // fragment-layout W: fully coalesced 16B/lane, L1-resident (16KB total)
        bf16x8 bf = __builtin_bit_cast(bf16x8, *(const ushort8*)(Wb + ((t * 4 + k) * 64 + lane) * 8));
        acc = __builtin_amdgcn_mfma_f32_16x16x32_bf16(af[k], bf, acc, 0, 0, 0);
      }
      const float bv = bb[t * 16 + col];  // precomputed bs+bn, L2-hot
      #pragma unroll
      for (int r = 0; r < 4; ++r) {
        const int orow = mt * 16 + quad * 4 + r;  // = nl*8 + b
        const int nl = orow >> 3, b = orow & 7;
        const float v = acc[r] + bv;
        __builtin_nontemporal_store(v > 0.f ? v : 0.f,
                                    &out[((size_t)b * Nn + node0 + nl) * Dd + t * 16 + col]);
      }
    }
  }
}

// ---- workspace layout ----
#define OFF_XB 0ull          // 51,200,000 B (bf16 x, transposed [node][batch][dim])
#define OFF_DEG 51200000ull  //    200,000 B (int per node)
#define OFF_BKT 51400000ull  //  6,400,000 B (ushort src, CAP=64 per node)
#define OFF_WB 57800000ull   //     16,384 B (bf16 W in MFMA fragment layout)
#define OFF_BB 57816384ull   //        256 B (f32 bias sum)
#define WS_NEED 57816640ull

extern "C" void kernel_launch(void* const* d_in, const int* in_sizes, int n_in,
                              void* d_out, int out_size, void* d_ws,
                              size_t ws_size, hipStream_t stream) {
  const float* x = (const float*)d_in[0];
  const int* ei = (const int*)d_in[1];  // (E,2) int32: [src,dst]
  const float* Ws = (const float*)d_in[2];
  const float* bs = (const float*)d_in[3];
  const float* Wn = (const float*)d_in[4];
  const float* bn = (const float*)d_in[5];
  float* out = (float*)d_out;

  if (ws_size < WS_NEED) return;

  char* ws = (char*)d_ws;
  unsigned short* xb = (unsigned short*)(ws + OFF_XB);
  int* deg = (int*)(ws + OFF_DEG);
  unsigned short* bucket = (unsigned short*)(ws + OFF_BKT);
  unsigned short* Wb = (unsigned short*)(ws + OFF_WB);
  float* bb = (float*)(ws + OFF_BB);

  hipMemsetAsync(deg, 0, Nn * sizeof(int), stream);
  // no bucket memset: k_main masks by (slot < cnt), junk slots never used
  k_fconv<<<(Bn * Nn * Dd / 8) / 256, 256, 0, stream>>>(x, xb, ei, deg, bucket, Ws, Wn, bs, bn, Wb, bb);
  k_main<<<Nn / 16, 256, 0, stream>>>(xb, bucket, deg, Wb, bb, out);
}